// Round 18
// baseline (354.984 us; speedup 1.0000x reference)
//
#include <hip/hip_runtime.h>
#include <hip/hip_bf16.h>
#include <cstdint>
#include <cstddef>

// ---------------------------------------------------------------------------
// HopfieldModel: z = x@W_enc; 4x { q <- softmax(2 q K^T) K } per network;
// out = log_softmax(relu(concat q) @ W_lin + b_lin)
//
// scan v6 (round-17 lesson): register-level prefetch is DEFEATED by the HIP
//   scheduler (VGPR stayed 120 with launch_bounds(,1): the compiler sank all
//   loads to their MFMA uses; WRITE_SIZE 6.4MB was candidate flush, not
//   spill).  New structure = the guide's verified 2-phase LDS pipeline:
//   - block covers 64 q-rows x its chunk's full 1024 keys (32 tiles of 32).
//   - each wave owns 16 q-rows (aq = 16 VGPR); all 4 waves share each
//     LDS-staged key tile -> keys staged ONCE per block.
//   - reg-staged ds_write AFTER compute (T14 split): the late LDS-write use
//     lets the global load issue early and its latency hide under MFMA.
//   - XOR swizzle (byte ^= (key&7)<<4) on ds_write/ds_read kills the 16-way
//     bank conflict of 256B-stride rows (G4).
//   - per-wave running max now spans the WHOLE chunk -> chunk-anchored
//     thresholds (~5-10 emissions/cell, round-8 regime).  Superset proof
//     unchanged: running max <= global max.
// dense v3 (unchanged): quarter-items, coalesced scoring, compact PV.
// refine v2 (unchanged): parallel worklist match, flattened gather, exact
//   fp32 rescore, flash-merge, exact softmax + PV.
// ---------------------------------------------------------------------------

#define NNET 4
#define NQ   256
#define EDIM 128
#define NKEY 32768
#define ESTR 129              // embeddings row stride (col 128 dropped)
#define QT   64               // q rows per scan block
#define NCHUNK 32
#define KPC  (NKEY/NCHUNK)    // 1024 keys per chunk
#define KQ   256              // keys per dense quarter-item
#define SCAN_WAVES 4
#define NTILE 32              // 32-key tiles per chunk
#define BLOCKCAP 64           // cand slots per (query, chunk); log2 = 6
#define SURV_CAP 512
#define WCAP 1024             // worklist capacity per step
#define MITCAP 128            // matched items per slot (structural max)
#define EMIT_MARGIN 10.0f     // emission band below running wave max
#define SEL_MARGIN  9.5f      // stored-score filter below global max
#define REL_MARGIN  9.75f     // chunk relevance: cmax >= G - REL

typedef _Float16 half8 __attribute__((ext_vector_type(8)));
typedef float f32x4v __attribute__((ext_vector_type(4)));

__device__ __forceinline__ float dec16(unsigned v) {
  _Float16 h = __builtin_bit_cast(_Float16, (unsigned short)(v & 0xFFFFu));
  return (float)h;
}
__device__ __forceinline__ unsigned pack16(int key, float s) {
  unsigned short hb = __builtin_bit_cast(unsigned short, (_Float16)s);
  return ((unsigned)key << 16) | (unsigned)hb;
}
__device__ __forceinline__ unsigned enc_f32(float f) {
  unsigned u = __float_as_uint(f);
  return (u & 0x80000000u) ? ~u : (u | 0x80000000u);  // order-preserving
}
__device__ __forceinline__ float dec_f32(unsigned e) {
  unsigned u = (e & 0x80000000u) ? (e & 0x7FFFFFFFu) : ~e;
  return __uint_as_float(u);
}

// --------------------------- encoder: z = x@We + be -------------------------
__global__ __launch_bounds__(128)
void enc_kernel(const float* __restrict__ x, const float* __restrict__ We,
                const float* __restrict__ be, float* __restrict__ q0,
                int* __restrict__ gw) {
  const int b = blockIdx.x, tid = threadIdx.x;
  __shared__ float xs[784];
  for (int i = tid; i < 784; i += 128) xs[i] = x[b * 784 + i];
  __syncthreads();
  float acc = be[tid];
  for (int i = 0; i < 784; ++i) acc += xs[i] * We[i * EDIM + tid];
#pragma unroll
  for (int n = 0; n < NNET; ++n) q0[((size_t)n * NQ + b) * EDIM + tid] = acc;
  if (b == 0 && tid < 4) gw[tid] = 0;   // per-step worklist counters
}

// ------------------- keyprep: embeddings f32 -> fp16 (drop col 128) --------
typedef _Float16 half4v __attribute__((ext_vector_type(4)));
__global__ __launch_bounds__(256)
void keyprep_kernel(const float* __restrict__ emb, _Float16* __restrict__ kh) {
  const size_t quads = (size_t)NNET * NKEY * EDIM / 4;
  for (size_t i4 = (size_t)blockIdx.x * 256 + threadIdx.x; i4 < quads;
       i4 += (size_t)gridDim.x * 256) {
    const size_t row = i4 >> 5;
    const int col = (int)(i4 & 31) * 4;
    const float* src = emb + row * ESTR + col;
    half4v h;
#pragma unroll
    for (int j = 0; j < 4; ++j) h[j] = (_Float16)src[j];
    *(half4v*)(kh + i4 * 4) = h;
  }
}

// ------------------------------- scan --------------------------------------
// 512 blocks (1D), 256 threads = 4 waves; block covers 64 q rows x one
// chunk (1024 keys).  Wave w owns q rows [qt*64 + w*16, +16).
// Remap: wg = 32*window + 8*qt + xcd; chunk-group c = 8*window + xcd.
template <bool F16K>
__global__ __launch_bounds__(SCAN_WAVES * 64)
void scan_kernel(const float* __restrict__ qcur, const float* __restrict__ emb,
                 const _Float16* __restrict__ keysh,
                 int* __restrict__ cntb, float* __restrict__ cmaxb,
                 unsigned* __restrict__ cand,
                 int* __restrict__ gw, int* __restrict__ wit) {
  const int wg = blockIdx.x;
  const int xcd = wg & 7;
  const int qt = (wg >> 3) & 3;      // 0..3 (QT=64)
  const int window = wg >> 5;        // 16 windows of 32 blocks
  const int c = window * 8 + xcd;    // 0..127
  const int net = c >> 5, chunk = c & 31;

  const int tid = threadIdx.x;
  const int lane = tid & 63;
  const int w = tid >> 6;
  const int g = lane >> 4, ln = lane & 15;

  __shared__ _Float16 kbuf[2][NTILE * EDIM / NTILE * 32 * 4];  // placeholder sized below
  // NOTE: actual size needed = 2 x 32 keys x 128 f16 = 2 x 4096 halves
  __shared__ unsigned lmax[QT];
  __shared__ int lcnt[QT];
  __shared__ unsigned lbuf[QT][BLOCKCAP];
  if (tid < QT) { lmax[tid] = enc_f32(-3.4e38f); lcnt[tid] = 0; }

  // A fragments: wave w owns 16 q rows; lane row = ln, k = g*8 + f*32 + j.
  half8 aq[4];
  {
    const float* qb = qcur + ((size_t)net * NQ + qt * QT + w * 16) * EDIM;
#pragma unroll
    for (int f = 0; f < 4; ++f) {
      const float* p = qb + ln * EDIM + f * 32 + g * 8;
      half8 h;
#pragma unroll
      for (int j = 0; j < 8; ++j) h[j] = (_Float16)(2.0f * p[j]);
      aq[f] = h;
    }
  }

  const int key0 = chunk * KPC;
  const _Float16* ksrc = F16K ? (keysh + ((size_t)net * NKEY + key0) * EDIM) : nullptr;
  const float* esrc = emb + ((size_t)net * NKEY + key0) * ESTR;

  // 16B staging segments: sid in [0,512) covers one 8KB (32-key) tile.
  const int sid0 = tid, sid1 = tid + 256;
  auto swzoff = [&](int sid) {
    const int key = sid >> 4, seg = sid & 15;
    return key * 256 + ((seg * 16) ^ ((key & 7) << 4));   // bytes
  };
  const int woff0 = swzoff(sid0), woff1 = swzoff(sid1);

  auto loadSeg = [&](int tile, int sid) -> half8 {
    if constexpr (F16K) {
      return *(const half8*)(ksrc + (size_t)tile * 32 * EDIM + sid * 8);
    } else {
      const int key = sid >> 4, seg = sid & 15;
      const float* p = esrc + (size_t)(tile * 32 + key) * ESTR + seg * 8;
      half8 h;
#pragma unroll
      for (int j = 0; j < 8; ++j) h[j] = (_Float16)p[j];
      return h;
    }
  };

  // prologue: stage tile 0
  {
    half8 r0 = loadSeg(0, sid0), r1 = loadSeg(0, sid1);
    *(half8*)((char*)kbuf[0] + woff0) = r0;
    *(half8*)((char*)kbuf[0] + woff1) = r1;
  }
  __syncthreads();

  float rowmax[4];
#pragma unroll
  for (int r = 0; r < 4; ++r) rowmax[r] = -3.4e38f;
  const int q0l = w * 16 + 4 * g;        // this lane's first q row (local)
  const int rmask = (ln & 7) << 4;       // read-side XOR (same as write)

  for (int t = 0; t < NTILE; ++t) {
    const int cur = t & 1;
    const bool more = (t + 1) < NTILE;
    half8 r0, r1;
    if (more) { r0 = loadSeg(t + 1, sid0); r1 = loadSeg(t + 1, sid1); }

    f32x4v acc[2];
    acc[0] = f32x4v{0.f, 0.f, 0.f, 0.f};
    acc[1] = f32x4v{0.f, 0.f, 0.f, 0.f};
#pragma unroll
    for (int st = 0; st < 2; ++st) {
      const char* kb = (const char*)kbuf[cur] + (st * 16 + ln) * 256;
#pragma unroll
      for (int f = 0; f < 4; ++f) {
        const half8 bk = *(const half8*)(kb + ((f * 64 + g * 16) ^ rmask));
        acc[st] = __builtin_amdgcn_mfma_f32_16x16x32_f16(aq[f], bk, acc[st], 0, 0, 0);
      }
    }
    // running per-row max over all keys seen (rows 4g+r of this wave's 16)
#pragma unroll
    for (int st = 0; st < 2; ++st)
#pragma unroll
      for (int r = 0; r < 4; ++r) rowmax[r] = fmaxf(rowmax[r], acc[st][r]);
#pragma unroll
    for (int d = 1; d < 16; d <<= 1)
#pragma unroll
      for (int r = 0; r < 4; ++r)
        rowmax[r] = fmaxf(rowmax[r], __shfl_xor(rowmax[r], d, 64));
    // emit against the running (monotone, <= global-max) threshold
#pragma unroll
    for (int st = 0; st < 2; ++st) {
      const int keyg = key0 + t * 32 + st * 16 + ln;
#pragma unroll
      for (int r = 0; r < 4; ++r)
        if (acc[st][r] >= rowmax[r] - EMIT_MARGIN) {
          const int q = q0l + r;
          const int slot = atomicAdd(&lcnt[q], 1);
          if (slot < BLOCKCAP) lbuf[q][slot] = pack16(keyg, acc[st][r]);
        }
    }
    // T14 late write: stage tile t+1 into the other buffer
    if (more) {
      *(half8*)((char*)kbuf[cur ^ 1] + woff0) = r0;
      *(half8*)((char*)kbuf[cur ^ 1] + woff1) = r1;
    }
    __syncthreads();
  }

  // publish per-(wave,row-group) chunk max
  if (ln == 0) {
#pragma unroll
    for (int r = 0; r < 4; ++r)
      atomicMax(&lmax[q0l + r], enc_f32(rowmax[r]));
  }
  __syncthreads();

  // ---- flush: fixed per-(query,chunk) region, plain stores ----
  const size_t qbase = (size_t)net * NQ + qt * QT;
  for (int j = tid; j < QT * BLOCKCAP; j += SCAN_WAVES * 64) {
    const int q = j >> 6, i = j & (BLOCKCAP - 1);
    const int cq = lcnt[q];
    if (i < (cq < BLOCKCAP ? cq : BLOCKCAP))
      cand[((qbase + q) * NCHUNK + chunk) * BLOCKCAP + i] = lbuf[q][i];
  }
  if (tid < QT) {
    const size_t cell = (qbase + tid) * NCHUNK + chunk;
    cntb[cell] = lcnt[tid];   // >BLOCKCAP => overflow (handled by dense kernel)
    cmaxb[cell] = dec_f32(lmax[tid]);
    if (lcnt[tid] > BLOCKCAP) {
      int i = atomicAdd(gw, 4);
#pragma unroll
      for (int qq = 0; qq < 4; ++qq)
        if (i + qq < WCAP) wit[i + qq] = ((int)cell << 2) | qq;
    }
  }
}

// ------------------------------- dense -------------------------------------
// one block per worklist QUARTER-item (256 keys of an overflowed cell).
__global__ __launch_bounds__(256)
void dense_kernel(const float* __restrict__ qcur, const float* __restrict__ emb,
                  const int* __restrict__ gw, const int* __restrict__ wit,
                  float* __restrict__ pm, float* __restrict__ pl,
                  float* __restrict__ po) {
  const int tid = threadIdx.x, lane = tid & 63, w = tid >> 6;
  const int grp = lane >> 3;   // key-within-pass
  const int le = lane & 7;     // element sub-lane
  int nwork = *gw;
  if (nwork > WCAP) nwork = WCAP;

  __shared__ float qv[EDIM];
  __shared__ float sc[KQ];
  __shared__ int klist[KQ];
  __shared__ float osh[EDIM];
  __shared__ float red[8];
  __shared__ int nsig;

  for (int it = blockIdx.x; it < nwork; it += gridDim.x) {
    const int v = wit[it];
    const int slot = v >> 7;                   // cell = v>>2; slot = cell/32
    const int chunk = (v >> 2) & 31;
    const int qq = v & 3;
    const int net = slot >> 8;
    const int kbase = chunk * KPC + qq * KQ;   // first key of this quarter

    if (tid < EDIM) qv[tid] = 2.0f * qcur[(size_t)slot * EDIM + tid];
    if (tid == 0) nsig = 0;
    __syncthreads();

    // exact fp32 scores: per wave 64 keys; 8 keys/pass, 4 passes in flight
    const float* base = emb + ((size_t)net * NKEY + kbase) * ESTR;
    for (int pp = 0; pp < 8; pp += 4) {
      float s[4] = {0.f, 0.f, 0.f, 0.f};
      const float* kr[4];
#pragma unroll
      for (int u = 0; u < 4; ++u)
        kr[u] = base + (size_t)(w * 64 + (pp + u) * 8 + grp) * ESTR + le;
#pragma unroll
      for (int i = 0; i < 16; ++i) {
        const float qe = qv[le + 8 * i];
#pragma unroll
        for (int u = 0; u < 4; ++u) s[u] += qe * kr[u][8 * i];
      }
#pragma unroll
      for (int d = 1; d < 8; d <<= 1)
#pragma unroll
        for (int u = 0; u < 4; ++u) s[u] += __shfl_xor(s[u], d, 64);
      if (le == 0) {
#pragma unroll
        for (int u = 0; u < 4; ++u) sc[w * 64 + (pp + u) * 8 + grp] = s[u];
      }
    }
    __syncthreads();

    // block max (1 key/thread)
    float m = sc[tid];
#pragma unroll
    for (int d = 32; d; d >>= 1) m = fmaxf(m, __shfl_xor(m, d, 64));
    if (lane == 0) red[w] = m;
    __syncthreads();
    const float m_c = fmaxf(fmaxf(red[0], red[1]), fmaxf(red[2], red[3]));

    // exp + sum + compact significant weights
    const float ev = expf(sc[tid] - m_c);
    sc[tid] = ev;
    float l = ev;
#pragma unroll
    for (int d = 32; d; d >>= 1) l += __shfl_xor(l, d, 64);
    if (lane == 0) red[4 + w] = l;
    if (ev > 1e-9f) {
      const int pos = atomicAdd(&nsig, 1);
      klist[pos] = tid;
    }
    __syncthreads();
    const float l_c = red[4] + red[5] + red[6] + red[7];
    const int msig = nsig;

    // PV over the compact list only (~tens of rows), half-split coalesced
    const int e = tid & 127, hf = tid >> 7;
    float acc = 0.f;
    for (int j = hf; j < msig; j += 2) {
      const int kk = klist[j];
      acc += sc[kk] * emb[((size_t)net * NKEY + kbase + kk) * ESTR + e];
    }
    if (hf) osh[e] = acc;
    __syncthreads();
    if (!hf) po[(size_t)it * EDIM + e] = acc + osh[e];
    if (tid == 0) { pm[it] = m_c; pl[it] = l_c; }
    __syncthreads();   // LDS reuse barrier before next item
  }
}

// ------------------------------- refine ------------------------------------
__global__ __launch_bounds__(256)
void refine_kernel(const float* __restrict__ qcur, const float* __restrict__ emb,
                   const int* __restrict__ cntb, const float* __restrict__ cmaxb,
                   const unsigned* __restrict__ cand, float* __restrict__ qnext,
                   const int* __restrict__ gw, const int* __restrict__ wit,
                   const float* __restrict__ pm, const float* __restrict__ pl,
                   const float* __restrict__ po) {
  const int q = blockIdx.x, net = blockIdx.y;
  const int tid = threadIdx.x, lane = tid & 63, w = tid >> 6;
  const int slot = net * NQ + q;
  __shared__ float qv[EDIM];
  __shared__ float osh[EDIM];
  __shared__ int ccnt[NCHUNK];
  __shared__ float cmax[NCHUNK];
  __shared__ int keys[SURV_CAP];
  __shared__ float exsc[SURV_CAP];
  __shared__ int mit[MITCAP];
  __shared__ int nmit;
  __shared__ int nsurv;
  __shared__ float gmax_s;
  __shared__ float red[8];

  int nwork = *gw;
  if (nwork > WCAP) nwork = WCAP;

  if (tid < EDIM) qv[tid] = 2.0f * qcur[(size_t)slot * EDIM + tid];
  if (tid < NCHUNK) {
    ccnt[tid] = cntb[(size_t)slot * NCHUNK + tid];
    cmax[tid] = cmaxb[(size_t)slot * NCHUNK + tid];
  }
  if (tid == 0) { nsurv = 0; nmit = 0; }
  __syncthreads();
  if (tid == 0) {
    float gv = -3.4e38f;
    for (int c = 0; c < NCHUNK; ++c) gv = fmaxf(gv, cmax[c]);
    gmax_s = gv;
  }
  // ---- parallel worklist matching (all threads, one strided pass) ----
  for (int it = tid; it < nwork; it += 256) {
    if ((wit[it] >> 7) == slot) {
      const int i = atomicAdd(&nmit, 1);
      if (i < MITCAP) mit[i] = it;
    }
  }
  __syncthreads();
  const float G = gmax_s;
  const int nm = nmit < MITCAP ? nmit : MITCAP;

  // ---- flattened survivor gather over (chunk, idx) pairs ----
  for (int j = tid; j < NCHUNK * BLOCKCAP; j += 256) {
    const int c = j >> 6, i = j & (BLOCKCAP - 1);
    if (cmax[c] < G - REL_MARGIN) continue;   // irrelevant chunk
    const int cc = ccnt[c];
    if (cc > BLOCKCAP) continue;              // overflowed: dense path
    if (i < cc) {
      const unsigned pv = cand[((size_t)slot * NCHUNK + c) * BLOCKCAP + i];
      if (dec16(pv) >= G - SEL_MARGIN) {
        const int k = atomicAdd(&nsurv, 1);
        if (k < SURV_CAP) keys[k] = (int)(pv >> 16);
      }
    }
  }
  __syncthreads();
  int m = nsurv < SURV_CAP ? nsurv : SURV_CAP;

  // ---- exact fp32 scores for the m survivors ----
  for (int j = w; j < m; j += 4) {
    const float* kr = emb + ((size_t)net * NKEY + keys[j]) * ESTR;
    float p2 = qv[2 * lane] * kr[2 * lane] + qv[2 * lane + 1] * kr[2 * lane + 1];
#pragma unroll
    for (int d = 32; d; d >>= 1) p2 += __shfl_xor(p2, d, 64);
    if (lane == 0) exsc[j] = p2;
  }
  __syncthreads();
  if (w == 0) {
    float em = -3.4e38f;
    for (int j = lane; j < m; j += 64) em = fmaxf(em, exsc[j]);
#pragma unroll
    for (int d = 32; d; d >>= 1) em = fmaxf(em, __shfl_xor(em, d, 64));
    if (lane == 0) red[0] = em;
  }
  __syncthreads();
  const float em = red[0];
  for (int j = tid; j < m; j += 256) exsc[j] = expf(exsc[j] - em);
  __syncthreads();
  if (w == 0) {
    float l = 0.f;
    for (int j = lane; j < m; j += 64) l += exsc[j];
#pragma unroll
    for (int d = 32; d; d >>= 1) l += __shfl_xor(l, d, 64);
    if (lane == 0) red[1] = l;
  }
  __syncthreads();

  // ---- merge scalars with matched dense partials (flash combine) ----
  if (tid == 0) {
    float mstar = (m > 0) ? em : -3.4e38f;
    for (int j = 0; j < nm; ++j) mstar = fmaxf(mstar, pm[mit[j]]);
    float ltot = (m > 0) ? red[1] * expf(em - mstar) : 0.f;
    for (int j = 0; j < nm; ++j) ltot += pl[mit[j]] * expf(pm[mit[j]] - mstar);
    red[2] = mstar;
    red[3] = ltot;
  }
  __syncthreads();
  const float mstar = red[2];
  const float inv = 1.0f / red[3];

  // ---- exact PV over survivors + merged partial o ----
  const int e = tid & 127, hf = tid >> 7;
  float acc = 0.f;
  for (int j = hf; j < m; j += 2)
    acc += exsc[j] * emb[((size_t)net * NKEY + keys[j]) * ESTR + e];
  if (hf) osh[e] = acc;
  __syncthreads();
  if (!hf) {
    float o = (m > 0) ? (acc + osh[e]) * expf(em - mstar) : 0.f;
    for (int j = 0; j < nm; ++j)
      o += po[(size_t)mit[j] * EDIM + e] * expf(pm[mit[j]] - mstar);
    qnext[(size_t)slot * EDIM + e] = o * inv;
  }
}

// ------------------------------- head --------------------------------------
__global__ __launch_bounds__(64)
void head_kernel(const float* __restrict__ qf, const float* __restrict__ Wl,
                 const float* __restrict__ bl, float* __restrict__ out) {
  const int b = blockIdx.x, lane = threadIdx.x;
  float acc[10];
#pragma unroll
  for (int c = 0; c < 10; ++c) acc[c] = 0.f;
  for (int t = lane; t < NNET * EDIM; t += 64) {
    float z = qf[((size_t)(t >> 7) * NQ + b) * EDIM + (t & 127)];
    z = fmaxf(z, 0.f);
    const float* wr = Wl + t * 10;
#pragma unroll
    for (int c = 0; c < 10; ++c) acc[c] += z * wr[c];
  }
#pragma unroll
  for (int d = 32; d; d >>= 1)
#pragma unroll
    for (int c = 0; c < 10; ++c) acc[c] += __shfl_xor(acc[c], d, 64);
  if (lane == 0) {
    float lg[10], mxv = -3.4e38f;
#pragma unroll
    for (int c = 0; c < 10; ++c) {
      lg[c] = acc[c] + bl[c];
      mxv = fmaxf(mxv, lg[c]);
    }
    float s = 0.f;
#pragma unroll
    for (int c = 0; c < 10; ++c) s += expf(lg[c] - mxv);
    float lse = mxv + logf(s);
#pragma unroll
    for (int c = 0; c < 10; ++c) out[b * 10 + c] = lg[c] - lse;
  }
}

// ------------------------------- launch ------------------------------------
extern "C" void kernel_launch(void* const* d_in, const int* in_sizes, int n_in,
                              void* d_out, int out_size, void* d_ws, size_t ws_size,
                              hipStream_t stream) {
  (void)in_sizes; (void)n_in; (void)out_size;
  const float* x   = (const float*)d_in[0];
  const float* emb = (const float*)d_in[1];
  const float* We  = (const float*)d_in[2];
  const float* be  = (const float*)d_in[3];
  const float* Wl  = (const float*)d_in[4];
  const float* bl  = (const float*)d_in[5];
  float* out = (float*)d_out;

  char* p = (char*)d_ws;
  float* q0 = (float*)p;    p += (size_t)NNET * NQ * EDIM * 4;
  float* q1 = (float*)p;    p += (size_t)NNET * NQ * EDIM * 4;
  int* cntb = (int*)p;      p += (size_t)NNET * NQ * NCHUNK * 4;
  float* cmaxb = (float*)p; p += (size_t)NNET * NQ * NCHUNK * 4;
  unsigned* cand = (unsigned*)p; p += (size_t)NNET * NQ * NCHUNK * BLOCKCAP * 4;
  int* gw = (int*)p;        p += 16;                 // 4 per-step counters
  int* wit = (int*)p;       p += (size_t)4 * WCAP * 4;
  float* pm = (float*)p;    p += (size_t)WCAP * 4;
  float* pl = (float*)p;    p += (size_t)WCAP * 4;
  float* po = (float*)p;    p += (size_t)WCAP * EDIM * 4;
  _Float16* kh = (_Float16*)p;
  const bool f16k =
      ((size_t)(p - (char*)d_ws) + (size_t)NNET * NKEY * EDIM * 2) <= ws_size;

  enc_kernel<<<dim3(NQ), dim3(128), 0, stream>>>(x, We, be, q0, gw);
  if (f16k)
    keyprep_kernel<<<dim3(4096), dim3(256), 0, stream>>>(emb, kh);

  const int nblocks = NNET * NCHUNK * (NQ / QT);  // 512
  float* qa = q0;
  float* qb = q1;
  for (int step = 0; step < 4; ++step) {
    int* gws = gw + step;
    int* wits = wit + step * WCAP;
    if (f16k)
      scan_kernel<true><<<dim3(nblocks), dim3(SCAN_WAVES * 64), 0, stream>>>(
          qa, emb, kh, cntb, cmaxb, cand, gws, wits);
    else
      scan_kernel<false><<<dim3(nblocks), dim3(SCAN_WAVES * 64), 0, stream>>>(
          qa, emb, (const _Float16*)nullptr, cntb, cmaxb, cand, gws, wits);
    dense_kernel<<<dim3(256), dim3(256), 0, stream>>>(qa, emb, gws, wits, pm, pl, po);
    refine_kernel<<<dim3(NQ, NNET), dim3(256), 0, stream>>>(
        qa, emb, cntb, cmaxb, cand, qb, gws, wits, pm, pl, po);
    float* t = qa; qa = qb; qb = t;
  }
  head_kernel<<<dim3(NQ), dim3(64), 0, stream>>>(qa, Wl, bl, out);
}

// Round 19
// 246.800 us; speedup vs baseline: 1.4384x; 1.4384x over previous
//
#include <hip/hip_runtime.h>
#include <hip/hip_bf16.h>
#include <cstdint>
#include <cstddef>

// ---------------------------------------------------------------------------
// HopfieldModel: z = x@W_enc; 4x { q <- softmax(2 q K^T) K } per network;
// out = log_softmax(relu(concat q) @ W_lin + b_lin)
//
// scan v6.1 (round-18 lesson): v6's kbuf was accidentally sized 64KB ->
//   82KB LDS/block -> 1 block/CU -> two serialized grid passes at 10%
//   occupancy (74us).  Correct size is 2 x 8KB (32 keys x 128 f16 per
//   buffer); total LDS ~33KB -> 4 blocks/CU cap, 2 resident for our grid.
//   Structure unchanged: block = 64 q rows x full 1024-key chunk; keys
//   staged once per block into double-buffered swizzled LDS (T14 write-
//   after-compute so loads issue early); chunk-anchored running-max
//   emission (superset proof: running max <= global max).
// dense v3 (unchanged): quarter-items, coalesced scoring, compact PV.
// refine v2 (unchanged): parallel worklist match, flattened gather, exact
//   fp32 rescore, flash-merge, exact softmax + PV.
// ---------------------------------------------------------------------------

#define NNET 4
#define NQ   256
#define EDIM 128
#define NKEY 32768
#define ESTR 129              // embeddings row stride (col 128 dropped)
#define QT   64               // q rows per scan block
#define NCHUNK 32
#define KPC  (NKEY/NCHUNK)    // 1024 keys per chunk
#define KQ   256              // keys per dense quarter-item
#define SCAN_WAVES 4
#define NTILE 32              // 32-key tiles per chunk
#define BLOCKCAP 64           // cand slots per (query, chunk); log2 = 6
#define SURV_CAP 512
#define WCAP 1024             // worklist capacity per step
#define MITCAP 128            // matched items per slot (structural max)
#define EMIT_MARGIN 10.0f     // emission band below running wave max
#define SEL_MARGIN  9.5f      // stored-score filter below global max
#define REL_MARGIN  9.75f     // chunk relevance: cmax >= G - REL

typedef _Float16 half8 __attribute__((ext_vector_type(8)));
typedef float f32x4v __attribute__((ext_vector_type(4)));

__device__ __forceinline__ float dec16(unsigned v) {
  _Float16 h = __builtin_bit_cast(_Float16, (unsigned short)(v & 0xFFFFu));
  return (float)h;
}
__device__ __forceinline__ unsigned pack16(int key, float s) {
  unsigned short hb = __builtin_bit_cast(unsigned short, (_Float16)s);
  return ((unsigned)key << 16) | (unsigned)hb;
}
__device__ __forceinline__ unsigned enc_f32(float f) {
  unsigned u = __float_as_uint(f);
  return (u & 0x80000000u) ? ~u : (u | 0x80000000u);  // order-preserving
}
__device__ __forceinline__ float dec_f32(unsigned e) {
  unsigned u = (e & 0x80000000u) ? (e & 0x7FFFFFFFu) : ~e;
  return __uint_as_float(u);
}

// --------------------------- encoder: z = x@We + be -------------------------
__global__ __launch_bounds__(128)
void enc_kernel(const float* __restrict__ x, const float* __restrict__ We,
                const float* __restrict__ be, float* __restrict__ q0,
                int* __restrict__ gw) {
  const int b = blockIdx.x, tid = threadIdx.x;
  __shared__ float xs[784];
  for (int i = tid; i < 784; i += 128) xs[i] = x[b * 784 + i];
  __syncthreads();
  float acc = be[tid];
  for (int i = 0; i < 784; ++i) acc += xs[i] * We[i * EDIM + tid];
#pragma unroll
  for (int n = 0; n < NNET; ++n) q0[((size_t)n * NQ + b) * EDIM + tid] = acc;
  if (b == 0 && tid < 4) gw[tid] = 0;   // per-step worklist counters
}

// ------------------- keyprep: embeddings f32 -> fp16 (drop col 128) --------
typedef _Float16 half4v __attribute__((ext_vector_type(4)));
__global__ __launch_bounds__(256)
void keyprep_kernel(const float* __restrict__ emb, _Float16* __restrict__ kh) {
  const size_t quads = (size_t)NNET * NKEY * EDIM / 4;
  for (size_t i4 = (size_t)blockIdx.x * 256 + threadIdx.x; i4 < quads;
       i4 += (size_t)gridDim.x * 256) {
    const size_t row = i4 >> 5;
    const int col = (int)(i4 & 31) * 4;
    const float* src = emb + row * ESTR + col;
    half4v h;
#pragma unroll
    for (int j = 0; j < 4; ++j) h[j] = (_Float16)src[j];
    *(half4v*)(kh + i4 * 4) = h;
  }
}

// ------------------------------- scan --------------------------------------
// 512 blocks (1D), 256 threads = 4 waves; block covers 64 q rows x one
// chunk (1024 keys).  Wave w owns q rows [qt*64 + w*16, +16).
// Remap: wg = 32*window + 8*qt + xcd; chunk-group c = 8*window + xcd.
template <bool F16K>
__global__ __launch_bounds__(SCAN_WAVES * 64)
void scan_kernel(const float* __restrict__ qcur, const float* __restrict__ emb,
                 const _Float16* __restrict__ keysh,
                 int* __restrict__ cntb, float* __restrict__ cmaxb,
                 unsigned* __restrict__ cand,
                 int* __restrict__ gw, int* __restrict__ wit) {
  const int wg = blockIdx.x;
  const int xcd = wg & 7;
  const int qt = (wg >> 3) & 3;      // 0..3 (QT=64)
  const int window = wg >> 5;        // 16 windows of 32 blocks
  const int c = window * 8 + xcd;    // 0..127
  const int net = c >> 5, chunk = c & 31;

  const int tid = threadIdx.x;
  const int lane = tid & 63;
  const int w = tid >> 6;
  const int g = lane >> 4, ln = lane & 15;

  __shared__ _Float16 kbuf[2][32 * EDIM];   // 2 x 8KB: 32 keys x 128 f16
  __shared__ unsigned lmax[QT];
  __shared__ int lcnt[QT];
  __shared__ unsigned lbuf[QT][BLOCKCAP];
  if (tid < QT) { lmax[tid] = enc_f32(-3.4e38f); lcnt[tid] = 0; }

  // A fragments: wave w owns 16 q rows; lane row = ln, k = g*8 + f*32 + j.
  half8 aq[4];
  {
    const float* qb = qcur + ((size_t)net * NQ + qt * QT + w * 16) * EDIM;
#pragma unroll
    for (int f = 0; f < 4; ++f) {
      const float* p = qb + ln * EDIM + f * 32 + g * 8;
      half8 h;
#pragma unroll
      for (int j = 0; j < 8; ++j) h[j] = (_Float16)(2.0f * p[j]);
      aq[f] = h;
    }
  }

  const int key0 = chunk * KPC;
  const _Float16* ksrc = F16K ? (keysh + ((size_t)net * NKEY + key0) * EDIM) : nullptr;
  const float* esrc = emb + ((size_t)net * NKEY + key0) * ESTR;

  // 16B staging segments: sid in [0,512) covers one 8KB (32-key) tile.
  const int sid0 = tid, sid1 = tid + 256;
  auto swzoff = [&](int sid) {
    const int key = sid >> 4, seg = sid & 15;
    return key * 256 + ((seg * 16) ^ ((key & 7) << 4));   // bytes
  };
  const int woff0 = swzoff(sid0), woff1 = swzoff(sid1);

  auto loadSeg = [&](int tile, int sid) -> half8 {
    if constexpr (F16K) {
      return *(const half8*)(ksrc + (size_t)tile * 32 * EDIM + sid * 8);
    } else {
      const int key = sid >> 4, seg = sid & 15;
      const float* p = esrc + (size_t)(tile * 32 + key) * ESTR + seg * 8;
      half8 h;
#pragma unroll
      for (int j = 0; j < 8; ++j) h[j] = (_Float16)p[j];
      return h;
    }
  };

  // prologue: stage tile 0
  {
    half8 r0 = loadSeg(0, sid0), r1 = loadSeg(0, sid1);
    *(half8*)((char*)kbuf[0] + woff0) = r0;
    *(half8*)((char*)kbuf[0] + woff1) = r1;
  }
  __syncthreads();

  float rowmax[4];
#pragma unroll
  for (int r = 0; r < 4; ++r) rowmax[r] = -3.4e38f;
  const int q0l = w * 16 + 4 * g;        // this lane's first q row (local)
  const int rmask = (ln & 7) << 4;       // read-side XOR (same as write)

  for (int t = 0; t < NTILE; ++t) {
    const int cur = t & 1;
    const bool more = (t + 1) < NTILE;
    half8 r0, r1;
    if (more) { r0 = loadSeg(t + 1, sid0); r1 = loadSeg(t + 1, sid1); }

    f32x4v acc[2];
    acc[0] = f32x4v{0.f, 0.f, 0.f, 0.f};
    acc[1] = f32x4v{0.f, 0.f, 0.f, 0.f};
#pragma unroll
    for (int st = 0; st < 2; ++st) {
      const char* kb = (const char*)kbuf[cur] + (st * 16 + ln) * 256;
#pragma unroll
      for (int f = 0; f < 4; ++f) {
        const half8 bk = *(const half8*)(kb + ((f * 64 + g * 16) ^ rmask));
        acc[st] = __builtin_amdgcn_mfma_f32_16x16x32_f16(aq[f], bk, acc[st], 0, 0, 0);
      }
    }
    // running per-row max over all keys seen (rows 4g+r of this wave's 16)
#pragma unroll
    for (int st = 0; st < 2; ++st)
#pragma unroll
      for (int r = 0; r < 4; ++r) rowmax[r] = fmaxf(rowmax[r], acc[st][r]);
#pragma unroll
    for (int d = 1; d < 16; d <<= 1)
#pragma unroll
      for (int r = 0; r < 4; ++r)
        rowmax[r] = fmaxf(rowmax[r], __shfl_xor(rowmax[r], d, 64));
    // emit against the running (monotone, <= global-max) threshold
#pragma unroll
    for (int st = 0; st < 2; ++st) {
      const int keyg = key0 + t * 32 + st * 16 + ln;
#pragma unroll
      for (int r = 0; r < 4; ++r)
        if (acc[st][r] >= rowmax[r] - EMIT_MARGIN) {
          const int q = q0l + r;
          const int slot = atomicAdd(&lcnt[q], 1);
          if (slot < BLOCKCAP) lbuf[q][slot] = pack16(keyg, acc[st][r]);
        }
    }
    // T14 late write: stage tile t+1 into the other buffer
    if (more) {
      *(half8*)((char*)kbuf[cur ^ 1] + woff0) = r0;
      *(half8*)((char*)kbuf[cur ^ 1] + woff1) = r1;
    }
    __syncthreads();
  }

  // publish per-(wave,row-group) chunk max
  if (ln == 0) {
#pragma unroll
    for (int r = 0; r < 4; ++r)
      atomicMax(&lmax[q0l + r], enc_f32(rowmax[r]));
  }
  __syncthreads();

  // ---- flush: fixed per-(query,chunk) region, plain stores ----
  const size_t qbase = (size_t)net * NQ + qt * QT;
  for (int j = tid; j < QT * BLOCKCAP; j += SCAN_WAVES * 64) {
    const int q = j >> 6, i = j & (BLOCKCAP - 1);
    const int cq = lcnt[q];
    if (i < (cq < BLOCKCAP ? cq : BLOCKCAP))
      cand[((qbase + q) * NCHUNK + chunk) * BLOCKCAP + i] = lbuf[q][i];
  }
  if (tid < QT) {
    const size_t cell = (qbase + tid) * NCHUNK + chunk;
    cntb[cell] = lcnt[tid];   // >BLOCKCAP => overflow (handled by dense kernel)
    cmaxb[cell] = dec_f32(lmax[tid]);
    if (lcnt[tid] > BLOCKCAP) {
      int i = atomicAdd(gw, 4);
#pragma unroll
      for (int qq = 0; qq < 4; ++qq)
        if (i + qq < WCAP) wit[i + qq] = ((int)cell << 2) | qq;
    }
  }
}

// ------------------------------- dense -------------------------------------
// one block per worklist QUARTER-item (256 keys of an overflowed cell).
__global__ __launch_bounds__(256)
void dense_kernel(const float* __restrict__ qcur, const float* __restrict__ emb,
                  const int* __restrict__ gw, const int* __restrict__ wit,
                  float* __restrict__ pm, float* __restrict__ pl,
                  float* __restrict__ po) {
  const int tid = threadIdx.x, lane = tid & 63, w = tid >> 6;
  const int grp = lane >> 3;   // key-within-pass
  const int le = lane & 7;     // element sub-lane
  int nwork = *gw;
  if (nwork > WCAP) nwork = WCAP;

  __shared__ float qv[EDIM];
  __shared__ float sc[KQ];
  __shared__ int klist[KQ];
  __shared__ float osh[EDIM];
  __shared__ float red[8];
  __shared__ int nsig;

  for (int it = blockIdx.x; it < nwork; it += gridDim.x) {
    const int v = wit[it];
    const int slot = v >> 7;                   // cell = v>>2; slot = cell/32
    const int chunk = (v >> 2) & 31;
    const int qq = v & 3;
    const int net = slot >> 8;
    const int kbase = chunk * KPC + qq * KQ;   // first key of this quarter

    if (tid < EDIM) qv[tid] = 2.0f * qcur[(size_t)slot * EDIM + tid];
    if (tid == 0) nsig = 0;
    __syncthreads();

    // exact fp32 scores: per wave 64 keys; 8 keys/pass, 4 passes in flight
    const float* base = emb + ((size_t)net * NKEY + kbase) * ESTR;
    for (int pp = 0; pp < 8; pp += 4) {
      float s[4] = {0.f, 0.f, 0.f, 0.f};
      const float* kr[4];
#pragma unroll
      for (int u = 0; u < 4; ++u)
        kr[u] = base + (size_t)(w * 64 + (pp + u) * 8 + grp) * ESTR + le;
#pragma unroll
      for (int i = 0; i < 16; ++i) {
        const float qe = qv[le + 8 * i];
#pragma unroll
        for (int u = 0; u < 4; ++u) s[u] += qe * kr[u][8 * i];
      }
#pragma unroll
      for (int d = 1; d < 8; d <<= 1)
#pragma unroll
        for (int u = 0; u < 4; ++u) s[u] += __shfl_xor(s[u], d, 64);
      if (le == 0) {
#pragma unroll
        for (int u = 0; u < 4; ++u) sc[w * 64 + (pp + u) * 8 + grp] = s[u];
      }
    }
    __syncthreads();

    // block max (1 key/thread)
    float m = sc[tid];
#pragma unroll
    for (int d = 32; d; d >>= 1) m = fmaxf(m, __shfl_xor(m, d, 64));
    if (lane == 0) red[w] = m;
    __syncthreads();
    const float m_c = fmaxf(fmaxf(red[0], red[1]), fmaxf(red[2], red[3]));

    // exp + sum + compact significant weights
    const float ev = expf(sc[tid] - m_c);
    sc[tid] = ev;
    float l = ev;
#pragma unroll
    for (int d = 32; d; d >>= 1) l += __shfl_xor(l, d, 64);
    if (lane == 0) red[4 + w] = l;
    if (ev > 1e-9f) {
      const int pos = atomicAdd(&nsig, 1);
      klist[pos] = tid;
    }
    __syncthreads();
    const float l_c = red[4] + red[5] + red[6] + red[7];
    const int msig = nsig;

    // PV over the compact list only (~tens of rows), half-split coalesced
    const int e = tid & 127, hf = tid >> 7;
    float acc = 0.f;
    for (int j = hf; j < msig; j += 2) {
      const int kk = klist[j];
      acc += sc[kk] * emb[((size_t)net * NKEY + kbase + kk) * ESTR + e];
    }
    if (hf) osh[e] = acc;
    __syncthreads();
    if (!hf) po[(size_t)it * EDIM + e] = acc + osh[e];
    if (tid == 0) { pm[it] = m_c; pl[it] = l_c; }
    __syncthreads();   // LDS reuse barrier before next item
  }
}

// ------------------------------- refine ------------------------------------
__global__ __launch_bounds__(256)
void refine_kernel(const float* __restrict__ qcur, const float* __restrict__ emb,
                   const int* __restrict__ cntb, const float* __restrict__ cmaxb,
                   const unsigned* __restrict__ cand, float* __restrict__ qnext,
                   const int* __restrict__ gw, const int* __restrict__ wit,
                   const float* __restrict__ pm, const float* __restrict__ pl,
                   const float* __restrict__ po) {
  const int q = blockIdx.x, net = blockIdx.y;
  const int tid = threadIdx.x, lane = tid & 63, w = tid >> 6;
  const int slot = net * NQ + q;
  __shared__ float qv[EDIM];
  __shared__ float osh[EDIM];
  __shared__ int ccnt[NCHUNK];
  __shared__ float cmax[NCHUNK];
  __shared__ int keys[SURV_CAP];
  __shared__ float exsc[SURV_CAP];
  __shared__ int mit[MITCAP];
  __shared__ int nmit;
  __shared__ int nsurv;
  __shared__ float gmax_s;
  __shared__ float red[8];

  int nwork = *gw;
  if (nwork > WCAP) nwork = WCAP;

  if (tid < EDIM) qv[tid] = 2.0f * qcur[(size_t)slot * EDIM + tid];
  if (tid < NCHUNK) {
    ccnt[tid] = cntb[(size_t)slot * NCHUNK + tid];
    cmax[tid] = cmaxb[(size_t)slot * NCHUNK + tid];
  }
  if (tid == 0) { nsurv = 0; nmit = 0; }
  __syncthreads();
  if (tid == 0) {
    float gv = -3.4e38f;
    for (int c = 0; c < NCHUNK; ++c) gv = fmaxf(gv, cmax[c]);
    gmax_s = gv;
  }
  // ---- parallel worklist matching (all threads, one strided pass) ----
  for (int it = tid; it < nwork; it += 256) {
    if ((wit[it] >> 7) == slot) {
      const int i = atomicAdd(&nmit, 1);
      if (i < MITCAP) mit[i] = it;
    }
  }
  __syncthreads();
  const float G = gmax_s;
  const int nm = nmit < MITCAP ? nmit : MITCAP;

  // ---- flattened survivor gather over (chunk, idx) pairs ----
  for (int j = tid; j < NCHUNK * BLOCKCAP; j += 256) {
    const int c = j >> 6, i = j & (BLOCKCAP - 1);
    if (cmax[c] < G - REL_MARGIN) continue;   // irrelevant chunk
    const int cc = ccnt[c];
    if (cc > BLOCKCAP) continue;              // overflowed: dense path
    if (i < cc) {
      const unsigned pv = cand[((size_t)slot * NCHUNK + c) * BLOCKCAP + i];
      if (dec16(pv) >= G - SEL_MARGIN) {
        const int k = atomicAdd(&nsurv, 1);
        if (k < SURV_CAP) keys[k] = (int)(pv >> 16);
      }
    }
  }
  __syncthreads();
  int m = nsurv < SURV_CAP ? nsurv : SURV_CAP;

  // ---- exact fp32 scores for the m survivors ----
  for (int j = w; j < m; j += 4) {
    const float* kr = emb + ((size_t)net * NKEY + keys[j]) * ESTR;
    float p2 = qv[2 * lane] * kr[2 * lane] + qv[2 * lane + 1] * kr[2 * lane + 1];
#pragma unroll
    for (int d = 32; d; d >>= 1) p2 += __shfl_xor(p2, d, 64);
    if (lane == 0) exsc[j] = p2;
  }
  __syncthreads();
  if (w == 0) {
    float em = -3.4e38f;
    for (int j = lane; j < m; j += 64) em = fmaxf(em, exsc[j]);
#pragma unroll
    for (int d = 32; d; d >>= 1) em = fmaxf(em, __shfl_xor(em, d, 64));
    if (lane == 0) red[0] = em;
  }
  __syncthreads();
  const float em = red[0];
  for (int j = tid; j < m; j += 256) exsc[j] = expf(exsc[j] - em);
  __syncthreads();
  if (w == 0) {
    float l = 0.f;
    for (int j = lane; j < m; j += 64) l += exsc[j];
#pragma unroll
    for (int d = 32; d; d >>= 1) l += __shfl_xor(l, d, 64);
    if (lane == 0) red[1] = l;
  }
  __syncthreads();

  // ---- merge scalars with matched dense partials (flash combine) ----
  if (tid == 0) {
    float mstar = (m > 0) ? em : -3.4e38f;
    for (int j = 0; j < nm; ++j) mstar = fmaxf(mstar, pm[mit[j]]);
    float ltot = (m > 0) ? red[1] * expf(em - mstar) : 0.f;
    for (int j = 0; j < nm; ++j) ltot += pl[mit[j]] * expf(pm[mit[j]] - mstar);
    red[2] = mstar;
    red[3] = ltot;
  }
  __syncthreads();
  const float mstar = red[2];
  const float inv = 1.0f / red[3];

  // ---- exact PV over survivors + merged partial o ----
  const int e = tid & 127, hf = tid >> 7;
  float acc = 0.f;
  for (int j = hf; j < m; j += 2)
    acc += exsc[j] * emb[((size_t)net * NKEY + keys[j]) * ESTR + e];
  if (hf) osh[e] = acc;
  __syncthreads();
  if (!hf) {
    float o = (m > 0) ? (acc + osh[e]) * expf(em - mstar) : 0.f;
    for (int j = 0; j < nm; ++j)
      o += po[(size_t)mit[j] * EDIM + e] * expf(pm[mit[j]] - mstar);
    qnext[(size_t)slot * EDIM + e] = o * inv;
  }
}

// ------------------------------- head --------------------------------------
__global__ __launch_bounds__(64)
void head_kernel(const float* __restrict__ qf, const float* __restrict__ Wl,
                 const float* __restrict__ bl, float* __restrict__ out) {
  const int b = blockIdx.x, lane = threadIdx.x;
  float acc[10];
#pragma unroll
  for (int c = 0; c < 10; ++c) acc[c] = 0.f;
  for (int t = lane; t < NNET * EDIM; t += 64) {
    float z = qf[((size_t)(t >> 7) * NQ + b) * EDIM + (t & 127)];
    z = fmaxf(z, 0.f);
    const float* wr = Wl + t * 10;
#pragma unroll
    for (int c = 0; c < 10; ++c) acc[c] += z * wr[c];
  }
#pragma unroll
  for (int d = 32; d; d >>= 1)
#pragma unroll
    for (int c = 0; c < 10; ++c) acc[c] += __shfl_xor(acc[c], d, 64);
  if (lane == 0) {
    float lg[10], mxv = -3.4e38f;
#pragma unroll
    for (int c = 0; c < 10; ++c) {
      lg[c] = acc[c] + bl[c];
      mxv = fmaxf(mxv, lg[c]);
    }
    float s = 0.f;
#pragma unroll
    for (int c = 0; c < 10; ++c) s += expf(lg[c] - mxv);
    float lse = mxv + logf(s);
#pragma unroll
    for (int c = 0; c < 10; ++c) out[b * 10 + c] = lg[c] - lse;
  }
}

// ------------------------------- launch ------------------------------------
extern "C" void kernel_launch(void* const* d_in, const int* in_sizes, int n_in,
                              void* d_out, int out_size, void* d_ws, size_t ws_size,
                              hipStream_t stream) {
  (void)in_sizes; (void)n_in; (void)out_size;
  const float* x   = (const float*)d_in[0];
  const float* emb = (const float*)d_in[1];
  const float* We  = (const float*)d_in[2];
  const float* be  = (const float*)d_in[3];
  const float* Wl  = (const float*)d_in[4];
  const float* bl  = (const float*)d_in[5];
  float* out = (float*)d_out;

  char* p = (char*)d_ws;
  float* q0 = (float*)p;    p += (size_t)NNET * NQ * EDIM * 4;
  float* q1 = (float*)p;    p += (size_t)NNET * NQ * EDIM * 4;
  int* cntb = (int*)p;      p += (size_t)NNET * NQ * NCHUNK * 4;
  float* cmaxb = (float*)p; p += (size_t)NNET * NQ * NCHUNK * 4;
  unsigned* cand = (unsigned*)p; p += (size_t)NNET * NQ * NCHUNK * BLOCKCAP * 4;
  int* gw = (int*)p;        p += 16;                 // 4 per-step counters
  int* wit = (int*)p;       p += (size_t)4 * WCAP * 4;
  float* pm = (float*)p;    p += (size_t)WCAP * 4;
  float* pl = (float*)p;    p += (size_t)WCAP * 4;
  float* po = (float*)p;    p += (size_t)WCAP * EDIM * 4;
  _Float16* kh = (_Float16*)p;
  const bool f16k =
      ((size_t)(p - (char*)d_ws) + (size_t)NNET * NKEY * EDIM * 2) <= ws_size;

  enc_kernel<<<dim3(NQ), dim3(128), 0, stream>>>(x, We, be, q0, gw);
  if (f16k)
    keyprep_kernel<<<dim3(4096), dim3(256), 0, stream>>>(emb, kh);

  const int nblocks = NNET * NCHUNK * (NQ / QT);  // 512
  float* qa = q0;
  float* qb = q1;
  for (int step = 0; step < 4; ++step) {
    int* gws = gw + step;
    int* wits = wit + step * WCAP;
    if (f16k)
      scan_kernel<true><<<dim3(nblocks), dim3(SCAN_WAVES * 64), 0, stream>>>(
          qa, emb, kh, cntb, cmaxb, cand, gws, wits);
    else
      scan_kernel<false><<<dim3(nblocks), dim3(SCAN_WAVES * 64), 0, stream>>>(
          qa, emb, (const _Float16*)nullptr, cntb, cmaxb, cand, gws, wits);
    dense_kernel<<<dim3(256), dim3(256), 0, stream>>>(qa, emb, gws, wits, pm, pl, po);
    refine_kernel<<<dim3(NQ, NNET), dim3(256), 0, stream>>>(
        qa, emb, cntb, cmaxb, cand, qb, gws, wits, pm, pl, po);
    float* t = qa; qa = qb; qb = t;
  }
  head_kernel<<<dim3(NQ), dim3(64), 0, stream>>>(qa, Wl, bl, out);
}